// Round 4
// baseline (7570.374 us; speedup 1.0000x reference)
//
#include <hip/hip_runtime.h>
#include <hip/hip_fp16.h>
#include <cstdint>

#define TT 128   // time steps (= bucket_size)
#define BB 128   // batch
#define II 512   // input dim
#define HH 512   // hidden dim
#define DD 1024  // I + H
#define NC 513   // H + 1
#define NPAD 520 // row pitch for lnXW / vbuf (f16)
#define NT 36    // n-tiles of 16 in GEMM (576 padded cols)
#define EPSL 1e-5f

typedef _Float16 h2v __attribute__((ext_vector_type(2)));
typedef _Float16 h8v __attribute__((ext_vector_type(8)));
typedef float    f4v __attribute__((ext_vector_type(4)));

__device__ __forceinline__ ushort f2h(float f){
  return __builtin_bit_cast(ushort, __float2half(f));
}
__device__ __forceinline__ float h2f(ushort s){
  return __half2float(__builtin_bit_cast(__half, s));
}
__device__ __forceinline__ float hsig(float x){
  return fminf(fmaxf(0.2f * x + 0.5f, 0.f), 1.f);
}
__device__ __forceinline__ float ftanh(float x){
  float e = __expf(2.f * x);
  return 1.f - 2.f * __builtin_amdgcn_rcpf(e + 1.f);
}
__device__ __forceinline__ float fdot2f(uint u, uint t, float acc){
#if __has_builtin(__builtin_amdgcn_fdot2)
  return __builtin_amdgcn_fdot2(__builtin_bit_cast(h2v, u), __builtin_bit_cast(h2v, t), acc, false);
#else
  h2v a = __builtin_bit_cast(h2v, u), b = __builtin_bit_cast(h2v, t);
  acc = fmaf((float)a[0], (float)b[0], acc);
  return fmaf((float)a[1], (float)b[1], acc);
#endif
}

// ---------------- pre-pack W / U into MFMA B-fragment order (f16) ----------
__global__ void prepack_B(const float* __restrict__ src, ushort* __restrict__ dst){
  int idx = blockIdx.x * 256 + threadIdx.x;
  if (idx >= 128 * NT * 16 * 8) return;
  int kl = idx & 7;
  int ni = (idx >> 3) & 15;
  int nt = (idx >> 7) % NT;
  int kc = idx / (NT * 16 * 8);
  int k = kc * 8 + kl;
  int n = nt * 16 + ni;
  float v = (n < NC) ? src[k * NC + n] : 0.f;
  dst[idx] = f2h(v);
}

// ---------------- pre-pack U_hi (rows I..I+511) for the recurrence GEMV ----
// Upk4 uint idx = (kpg*512 + n)*4 + j holds f16 pair (U[I+8kpg+2j][n], U[I+8kpg+2j+1][n])
__global__ void prepack_Uhi(const float* __restrict__ U, uint* __restrict__ Upk4,
                            ushort* __restrict__ ucol){
  int idx = blockIdx.x * 256 + threadIdx.x;
  if (idx < 64 * 512 * 4){
    int j   = idx & 3;
    int n   = (idx >> 2) & 511;
    int kpg = idx >> 11;
    int k0  = II + 8 * kpg + 2 * j;
    ushort lo = f2h(U[(size_t)k0 * NC + n]);
    ushort hi = f2h(U[(size_t)(k0 + 1) * NC + n]);
    Upk4[idx] = (uint)lo | ((uint)hi << 16);
  }
  if (idx < 512) ucol[idx] = f2h(U[(size_t)(II + idx) * NC + (NC - 1)]);
}

// ---------------- fused GEMM (+ optional row-LayerNorm), f16 MFMA ----------
__global__ __launch_bounds__(1024) void gemm_ln(
    const float* __restrict__ A, int amode, int ksteps,
    const ushort* __restrict__ Bpk, ushort* __restrict__ out,
    int do_ln, const float* __restrict__ gam, const float* __restrict__ bet,
    const float* __restrict__ bias)
{
  __shared__ ushort As[64][40];
  __shared__ float red[4][4][16][2];
  int tid = threadIdx.x;
  int lane = tid & 63, wid = tid >> 6;
  int quad = lane >> 4, l16 = lane & 15;
  int wm = wid >> 2, wn = wid & 3;
  int blk = blockIdx.x;

  f4v acc[9];
#pragma unroll
  for (int i = 0; i < 9; i++) acc[i] = (f4v){0.f, 0.f, 0.f, 0.f};

  int arow = tid >> 4;
  int acp  = tid & 15;
  int r = blk * 64 + arow;
  const float* aptr;
  if (amode == 0){ int t = r >> 7, b = r & 127; aptr = A + ((size_t)(b * TT + t)) * II + acp * 2; }
  else           { aptr = A + (size_t)r * DD + acp * 2; }

  for (int ks = 0; ks < ksteps; ks++){
    __syncthreads();
    float2 a2 = *(const float2*)(aptr + ks * 32);
    uint pk = (uint)f2h(a2.x) | ((uint)f2h(a2.y) << 16);
    *(uint*)&As[arow][acp * 2] = pk;
    __syncthreads();
    h8v af = *(const h8v*)&As[wm * 16 + l16][quad * 8];
    int kc = ks * 4 + quad;
    const h8v* bp = (const h8v*)Bpk + (size_t)kc * (NT * 16) + l16;
#pragma unroll
    for (int i = 0; i < 9; i++){
      h8v bf = bp[(wn * 9 + i) * 16];
      acc[i] = __builtin_amdgcn_mfma_f32_16x16x32_f16(af, bf, acc[i], 0, 0, 0);
    }
  }

  int rowbase = blk * 64 + wm * 16 + quad * 4;
  if (do_ln){
    float s1[4], s2[4];
#pragma unroll
    for (int g = 0; g < 4; g++){
      float a = 0.f, q = 0.f;
#pragma unroll
      for (int i = 0; i < 9; i++){ float v = acc[i][g]; a += v; q += v * v; }
#pragma unroll
      for (int m = 1; m < 16; m <<= 1){ a += __shfl_xor(a, m, 64); q += __shfl_xor(q, m, 64); }
      s1[g] = a; s2[g] = q;
    }
    if (l16 == 0){
#pragma unroll
      for (int g = 0; g < 4; g++){
        red[wm][wn][quad * 4 + g][0] = s1[g];
        red[wm][wn][quad * 4 + g][1] = s2[g];
      }
    }
    __syncthreads();
#pragma unroll
    for (int g = 0; g < 4; g++){
      int rr = quad * 4 + g;
      float S1 = red[wm][0][rr][0] + red[wm][1][rr][0] + red[wm][2][rr][0] + red[wm][3][rr][0];
      float S2 = red[wm][0][rr][1] + red[wm][1][rr][1] + red[wm][2][rr][1] + red[wm][3][rr][1];
      float mean = S1 * (1.f / 513.f);
      float var  = S2 * (1.f / 513.f) - mean * mean;
      float inv  = 1.f / (sqrtf(var + EPSL) + EPSL);
      size_t rg = (size_t)(rowbase + g);
#pragma unroll
      for (int i = 0; i < 9; i++){
        int n = wn * 144 + i * 16 + l16;
        if (n < NC){
          float val = gam[n] * ((acc[i][g] - mean) * inv) + bet[n] + bias[n];
          out[rg * NPAD + n] = f2h(val);
        }
      }
    }
  } else {
#pragma unroll
    for (int g = 0; g < 4; g++){
      size_t rg = (size_t)(rowbase + g);
#pragma unroll
      for (int i = 0; i < 9; i++){
        int n = wn * 144 + i * 16 + l16;
        if (n < NC) out[rg * NPAD + n] = f2h(acc[i][g]);
      }
    }
  }
}

// ---------------- 4-rows-per-block sequential recurrence -------------------
// 32 blocks, 512 threads. Block handles batch rows b0..b0+3; the 512 KB/t
// U_hi L2 stream is amortized over 4 rows. No cross-block communication.
// Thread tid owns GEMV column tid (all 4 rows) and h-dims {tid, tid+512}.
__global__ __launch_bounds__(512, 2) void rnn_layer(
    int layer,
    const float* __restrict__ x,
    float* __restrict__ h_seq,
    const ushort* __restrict__ lnXW,
    ushort* __restrict__ vbuf,
    float* __restrict__ fkbuf,
    float* __restrict__ hvbuf,
    const uint* __restrict__ Upk4,
    const ushort* __restrict__ ucol,
    const int* __restrict__ mask,
    const float* __restrict__ gam1, const float* __restrict__ bet1,
    const float* __restrict__ bias,
    float* __restrict__ out)
{
  __shared__ float  v[4][520];
  __shared__ ushort tanhvh[4][512];
  __shared__ float  statred[8][2];
  __shared__ float  p512red[4][8];
  __shared__ float  shg[4][2];          // [row]{s_col0, sum2_col0}
  __shared__ float  fkp_l[4][TT + 1];
  __shared__ float  hvp_l[4][TT];
  __shared__ unsigned char mkq[4][TT];

  const int tid  = threadIdx.x;
  const int b0   = blockIdx.x * 4;
  const int lane = tid & 63, wid = tid >> 6;

  // ---- one-time setup ----
  if (tid < TT){
#pragma unroll
    for (int r = 0; r < 4; r++){
      mkq[r][tid] = (unsigned char)(mask[(b0 + r) * TT + tid] > 0);
      if (layer == 0){ fkp_l[r][tid] = 0.f; hvp_l[r][tid] = 1.f; }
      else {
        fkp_l[r][tid] = fkbuf[tid * BB + b0 + r];
        hvp_l[r][tid] = hvbuf[tid * BB + b0 + r];
      }
    }
  }
  if (tid < 4) fkp_l[tid][TT] = 0.f;
#pragma unroll
  for (int r = 0; r < 4; r++) v[r][tid] = 0.f;
  if (tid < 4) v[tid][512] = 0.f;

  float g1n = gam1[tid], b1n = bet1[tid];
  float g1_512 = 0.f, b1_512 = 0.f;
  if (tid == 0){ g1_512 = gam1[512]; b1_512 = bet1[512]; }
  float b0r = bias[0];
  ushort ucolr = ucol[tid];

  float hlo[4] = {0.f, 0.f, 0.f, 0.f};
  float hhi[4] = {0.f, 0.f, 0.f, 0.f};
  float fk_c[4] = {0.f, 0.f, 0.f, 0.f};
  float hv_c[4] = {0.f, 0.f, 0.f, 0.f};

  const uint4* up = (const uint4*)Upk4 + tid;

  __syncthreads();

  for (int t = 0; t < TT; t++){
    // ---- phase 0: issue this step's independent global loads early ----
    size_t row[4];
    ushort lnx[4], xu[4];
    float xlo[4], xhi[4];
#pragma unroll
    for (int r = 0; r < 4; r++){
      row[r] = (size_t)(t * BB + b0 + r);
      lnx[r] = lnXW[row[r] * NPAD + tid];
      xu[r]  = vbuf[row[r] * NPAD + tid];
      if (layer == 0){
        xlo[r] = x[((size_t)(b0 + r) * TT + t) * II + tid];
        xhi[r] = 0.f;
      } else {
        xlo[r] = h_seq[row[r] * DD + tid];
        xhi[r] = h_seq[row[r] * DD + 512 + tid];
      }
    }
    ushort lnx512[4] = {0, 0, 0, 0};
    ushort xu512[4]  = {0, 0, 0, 0};
    if (tid == 0){
#pragma unroll
      for (int r = 0; r < 4; r++){
        lnx512[r] = lnXW[row[r] * NPAD + 512];
        xu512[r]  = vbuf[row[r] * NPAD + 512];
      }
    }

    // ---- stats: LN sums for all 4 rows (thread group r = tid>>7) ----
    {
      int sr = tid >> 7, si = tid & 127;
      float e0 = v[sr][si], e1 = v[sr][si + 128];
      float e2 = v[sr][si + 256], e3 = v[sr][si + 384];
      float a = (e0 + e1) + (e2 + e3);
      float q = (e0 * e0 + e1 * e1) + (e2 * e2 + e3 * e3);
      if (si == 0){ float e = v[sr][512]; a += e; q += e * e; }
#pragma unroll
      for (int m = 1; m < 64; m <<= 1){
        a += __shfl_xor(a, m, 64);
        q += __shfl_xor(q, m, 64);
      }
      if (lane == 0){ statred[wid][0] = a; statred[wid][1] = q; }
    }
    __syncthreads();   // (A)
    float mean[4], inv[4];
#pragma unroll
    for (int r = 0; r < 4; r++){
      float S = statred[2 * r][0] + statred[2 * r + 1][0];
      float Q = statred[2 * r][1] + statred[2 * r + 1][1];
      mean[r] = S * (1.f / 513.f);
      float var = Q * (1.f / 513.f) - mean[r] * mean[r];
      inv[r] = __builtin_amdgcn_rcpf(sqrtf(var + EPSL) + EPSL);
    }

    // ---- tanh for all 4 rows (thread tid -> col tid; col512 by tid 0) ----
#pragma unroll
    for (int r = 0; r < 4; r++){
      float sum2 = (v[r][tid] - mean[r]) * inv[r] * g1n + b1n;
      float s = h2f(lnx[r]) + sum2;
      if (tid != 0){
        tanhvh[r][tid - 1] = f2h(ftanh(s));
      } else {
        shg[r][0] = s; shg[r][1] = sum2;
        float s512 = h2f(lnx512[r]) + (v[r][512] - mean[r]) * inv[r] * g1_512 + b1_512;
        tanhvh[r][511] = f2h(ftanh(s512));
      }
    }
    __syncthreads();   // (B)

    // ---- gates (redundant on all threads, 4 rows) ----
    float ho[4], xo[4], bo[4];
    bool mk[4];
#pragma unroll
    for (int r = 0; r < 4; r++){
      mk[r] = mkq[r][t] != 0;
      bool mk2 = (t > 0) && (mkq[r][t - 1] != 0) && !mk[r];
      float fk_both = hsig(shg[r][0]);
      float fk_t1   = hsig(shg[r][1] + b0r);
      float fkp_tm1 = fkp_l[r][t], fkp = fkp_l[r][t + 1], hvp = hvp_l[r][t];
      float fk = fkp_tm1 + (1.f - fkp_tm1) * (fk_c[r] * fk_both + (1.f - fk_c[r]) * fk_t1);
      if (mk2) fk = 0.f;
      ho[r] = hv_c[r] * fk * (fkp + (1.f - fkp) * (1.f - hvp));
      xo[r] = hvp * (1.f - fkp) * (1.f - fk + fk * (1.f - hv_c[r]));
      bo[r] = (1.f - fkp) * fk * hv_c[r] * hvp;
      float hv = 1.f - (1.f - ho[r]) * (1.f - xo[r]) * (1.f - bo[r]);
      fk_c[r] = mk[r] ? fk : fk_c[r];
      hv_c[r] = mk[r] ? hv : hv_c[r];
      if (mk2) fk_c[r] = 0.f;
    }
    if (layer < 3 && tid == 0){
#pragma unroll
      for (int r = 0; r < 4; r++){
        fkbuf[t * BB + b0 + r] = fk_c[r];
        hvbuf[t * BB + b0 + r] = hv_c[r];
      }
    }

    // ---- col-512 partials (wave shuffle; read after barrier C) ----
    float th[4];
    {
      float uc = h2f(ucolr);
      float p0 = (th[0] = h2f(tanhvh[0][tid])) * uc;
      float p1 = (th[1] = h2f(tanhvh[1][tid])) * uc;
      float p2 = (th[2] = h2f(tanhvh[2][tid])) * uc;
      float p3 = (th[3] = h2f(tanhvh[3][tid])) * uc;
#pragma unroll
      for (int m = 1; m < 64; m <<= 1){
        p0 += __shfl_xor(p0, m, 64);
        p1 += __shfl_xor(p1, m, 64);
        p2 += __shfl_xor(p2, m, 64);
        p3 += __shfl_xor(p3, m, 64);
      }
      if (lane == 0){
        p512red[0][wid] = p0; p512red[1][wid] = p1;
        p512red[2][wid] = p2; p512red[3][wid] = p3;
      }
    }

    // ---- GEMV: y[r] = tanh[r] . U_hi[:, tid], U streamed from L2 ----
    float y0 = 0.f, y1 = 0.f, y2 = 0.f, y3 = 0.f;
    for (int kp = 0; kp < 64; kp++){
      uint4 u  = up[kp * 512];
      uint4 t0 = *(const uint4*)&tanhvh[0][8 * kp];
      uint4 t1 = *(const uint4*)&tanhvh[1][8 * kp];
      uint4 t2 = *(const uint4*)&tanhvh[2][8 * kp];
      uint4 t3 = *(const uint4*)&tanhvh[3][8 * kp];
      y0 = fdot2f(u.x, t0.x, y0); y0 = fdot2f(u.y, t0.y, y0);
      y0 = fdot2f(u.z, t0.z, y0); y0 = fdot2f(u.w, t0.w, y0);
      y1 = fdot2f(u.x, t1.x, y1); y1 = fdot2f(u.y, t1.y, y1);
      y1 = fdot2f(u.z, t1.z, y1); y1 = fdot2f(u.w, t1.w, y1);
      y2 = fdot2f(u.x, t2.x, y2); y2 = fdot2f(u.y, t2.y, y2);
      y2 = fdot2f(u.z, t2.z, y2); y2 = fdot2f(u.w, t2.w, y2);
      y3 = fdot2f(u.x, t3.x, y3); y3 = fdot2f(u.y, t3.y, y3);
      y3 = fdot2f(u.z, t3.z, y3); y3 = fdot2f(u.w, t3.w, y3);
    }

    // ---- h update (owned dims tid, tid+512; th[] from p512 phase) ----
#pragma unroll
    for (int r = 0; r < 4; r++){
      float nlo = ho[r] * hlo[r] + xo[r] * xlo[r];
      float nhi = ho[r] * hhi[r] + xo[r] * xhi[r] + bo[r] * th[r];
      if (mk[r]){ hlo[r] = nlo; hhi[r] = nhi; }
      if (layer < 3){
        h_seq[row[r] * DD + tid] = hlo[r];
        h_seq[row[r] * DD + 512 + tid] = hhi[r];
      }
    }
    if (layer == 3 && t == TT - 1){
#pragma unroll
      for (int r = 0; r < 4; r++) out[(size_t)(b0 + r) * HH + tid] = hhi[r];
    }
    __syncthreads();   // (C)

    // ---- v update (thread tid owns col tid; tid 0 also col 512) ----
    float yv[4] = {y0, y1, y2, y3};
#pragma unroll
    for (int r = 0; r < 4; r++){
      float nv = ho[r] * v[r][tid] + xo[r] * h2f(xu[r]) + bo[r] * yv[r];
      float vn = mk[r] ? nv : v[r][tid];
      v[r][tid] = vn;
      if (layer < 3) vbuf[row[r] * NPAD + tid] = f2h(vn);
    }
    if (tid == 0){
#pragma unroll
      for (int r = 0; r < 4; r++){
        float y512 = 0.f;
#pragma unroll
        for (int w = 0; w < 8; w++) y512 += p512red[r][w];
        float nv = ho[r] * v[r][512] + xo[r] * h2f(xu512[r]) + bo[r] * y512;
        float vn = mk[r] ? nv : v[r][512];
        v[r][512] = vn;
        if (layer < 3) vbuf[row[r] * NPAD + 512] = f2h(vn);
      }
    }
    __syncthreads();   // (D)
  }
}

extern "C" void kernel_launch(void* const* d_in, const int* in_sizes, int n_in,
                              void* d_out, int out_size, void* d_ws, size_t ws_size,
                              hipStream_t stream)
{
  (void)in_sizes; (void)n_in; (void)out_size; (void)ws_size;
  const float* x      = (const float*)d_in[0];
  const int*   mask   = (const int*)d_in[1];
  const float* W      = (const float*)d_in[2];
  const float* U      = (const float*)d_in[3];
  const float* bias   = (const float*)d_in[4];
  const float* gammas = (const float*)d_in[5];
  const float* betas  = (const float*)d_in[6];
  float* out = (float*)d_out;

  char* ws = (char*)d_ws;
  size_t off = 0;
  auto alloc = [&](size_t bytes) -> void* {
    void* p = ws + off;
    off += (bytes + 255) & ~(size_t)255;
    return p;
  };
  float*  h_seq = (float*) alloc((size_t)TT * BB * DD * 4);
  ushort* lnXW  = (ushort*)alloc((size_t)TT * BB * NPAD * 2);
  ushort* vbuf  = (ushort*)alloc((size_t)TT * BB * NPAD * 2);
  float*  fkbuf = (float*) alloc((size_t)TT * BB * 4);
  float*  hvbuf = (float*) alloc((size_t)TT * BB * 4);
  ushort* Wpk   = (ushort*)alloc((size_t)128 * NT * 16 * 8 * 2);
  ushort* Upk   = (ushort*)alloc((size_t)128 * NT * 16 * 8 * 2);
  uint*   Upk4  = (uint*)  alloc((size_t)64 * 512 * 4 * 4);
  ushort* ucol  = (ushort*)alloc(512 * 2);

  int npk = 128 * NT * 16 * 8;
  prepack_B<<<dim3((npk + 255) / 256), dim3(256), 0, stream>>>(W, Wpk);
  prepack_B<<<dim3((npk + 255) / 256), dim3(256), 0, stream>>>(U, Upk);
  prepack_Uhi<<<dim3((64 * 512 * 4 + 255) / 256), dim3(256), 0, stream>>>(U, Upk4, ucol);

  const float* g0 = gammas,      *g1 = gammas + NC;
  const float* be0 = betas,      *be1 = betas + NC;

  gemm_ln<<<dim3(256), dim3(1024), 0, stream>>>(x, 0, 16, Wpk, lnXW, 1, g0, be0, bias);
  gemm_ln<<<dim3(256), dim3(1024), 0, stream>>>(x, 0, 16, Upk, vbuf, 0, g0, be0, bias);
  rnn_layer<<<dim3(32), dim3(512), 0, stream>>>(0, x, h_seq, lnXW, vbuf, fkbuf, hvbuf,
                                                Upk4, ucol, mask, g1, be1, bias, out);
  for (int d = 1; d < 4; d++){
    gemm_ln<<<dim3(256), dim3(1024), 0, stream>>>(h_seq, 1, 32, Wpk, lnXW, 1, g0, be0, bias);
    rnn_layer<<<dim3(32), dim3(512), 0, stream>>>(d, x, h_seq, lnXW, vbuf, fkbuf, hvbuf,
                                                  Upk4, ucol, mask, g1, be1, bias, out);
  }
}